// Round 1
// baseline (272.547 us; speedup 1.0000x reference)
//
#include <hip/hip_runtime.h>
#include <stdint.h>

#define BATCH 32
#define CH    256
#define TLEN  4096
#define TN    64

typedef short    bf16x8 __attribute__((ext_vector_type(8)));
typedef float    f32x4  __attribute__((ext_vector_type(4)));
typedef uint32_t u32x4  __attribute__((ext_vector_type(4)));

__device__ __attribute__((aligned(16))) uint16_t g_w1eff[CH * CH];
__device__ float g_tap[CH * 5];
__device__ float g_bias[CH];

static __device__ __forceinline__ uint16_t f32_to_bf16(float f) {
    uint32_t u = __builtin_bit_cast(uint32_t, f);
    u += 0x7FFFu + ((u >> 16) & 1u);
    return (uint16_t)(u >> 16);
}
static __device__ __forceinline__ float bf16_to_f32(uint16_t h) {
    uint32_t u = ((uint32_t)h) << 16;
    return __builtin_bit_cast(float, u);
}
static __device__ __forceinline__ float gelu_exact(float v) {
    return 0.5f * v * (1.0f + erff(v * 0.70710678118654752f));
}

// Precompute: w1eff[o][c] = wc0[o]*w1[o][c] (bf16); 5-tap g[c]; fused bias[c].
__global__ void prep_kernel(const float* __restrict__ w1, const float* __restrict__ b1,
                            const float* __restrict__ w3, const float* __restrict__ b3,
                            const float* __restrict__ w5, const float* __restrict__ b5,
                            const float* __restrict__ wc, const float* __restrict__ bc) {
    const int o = blockIdx.x;
    const int c = threadIdx.x;
    const float wc0 = wc[o * 3 + 0];
    g_w1eff[o * CH + c] = f32_to_bf16(wc0 * w1[o * CH + c]);
    if (c == 0) {
        const float wc1 = wc[o * 3 + 1], wc2 = wc[o * 3 + 2];
        g_tap[o * 5 + 0] = wc2 * w5[o * 5 + 0];
        g_tap[o * 5 + 1] = wc1 * w3[o * 3 + 0] + wc2 * w5[o * 5 + 1];
        g_tap[o * 5 + 2] = wc1 * w3[o * 3 + 1] + wc2 * w5[o * 5 + 2];
        g_tap[o * 5 + 3] = wc1 * w3[o * 3 + 2] + wc2 * w5[o * 5 + 3];
        g_tap[o * 5 + 4] = wc2 * w5[o * 5 + 4];
        g_bias[o] = wc0 * b1[o] + wc1 * b3[o] + wc2 * b5[o] + bc[o];
    }
}

// Fused main kernel: per block = one (batch b, 64-timestep tile).
// LDS: a-tile [t=0..67][c=0..255] bf16 (t-major, XOR-swizzled),
//      w1eff K-chunk [co=0..255][k=0..31] bf16 (XOR-swizzled),
//      per-channel taps + bias.
__global__ __launch_bounds__(256, 2)
void fused_kernel(const float* __restrict__ x, float* __restrict__ out) {
    __shared__ __attribute__((aligned(16))) uint16_t sA[68 * CH];   // 34816 B
    __shared__ __attribute__((aligned(16))) uint16_t sW[CH * 32];   // 16384 B
    __shared__ float sBias[CH];                                     // 1024 B
    __shared__ float sTap[5 * CH];                                  // 5120 B

    const int tid  = threadIdx.x;
    const int lane = tid & 63;
    const int wid  = tid >> 6;
    const int b    = blockIdx.y;
    const int t0   = blockIdx.x * TN;

    // per-channel params into LDS
    {
        const int c = tid;
        sBias[c] = g_bias[c];
#pragma unroll
        for (int j = 0; j < 5; ++j) sTap[j * CH + c] = g_tap[c * 5 + j];
    }

    const float* __restrict__ xb = x + (size_t)b * CH * TLEN;

    // Stage a = gelu(x) tile with +/-2 halo. Wave w handles channels w, w+4, ...
    // Write swizzle: element (t,c) lives at sA[t*256 + (c ^ ((t&7)<<3))].
    for (int c = wid; c < CH; c += 4) {
        const float* xr = xb + (size_t)c * TLEN;
        {
            const int ti = lane;
            const int gt = t0 - 2 + ti;
            float v = (gt >= 0 && gt < TLEN) ? xr[gt] : 0.0f;
            sA[ti * CH + (c ^ ((ti & 7) << 3))] = f32_to_bf16(gelu_exact(v));
        }
        if (lane < 4) {
            const int ti = 64 + lane;
            const int gt = t0 - 2 + ti;
            float v = (gt < TLEN) ? xr[gt] : 0.0f;
            sA[ti * CH + (c ^ ((ti & 7) << 3))] = f32_to_bf16(gelu_exact(v));
        }
    }

    f32x4 acc[4][4];
    const f32x4 vzero = {0.f, 0.f, 0.f, 0.f};
#pragma unroll
    for (int mi = 0; mi < 4; ++mi)
#pragma unroll
        for (int ni = 0; ni < 4; ++ni) acc[mi][ni] = vzero;

    const int m0 = wid * 64;

    for (int kk = 0; kk < CH; kk += 32) {
        __syncthreads();
        // stage w1eff chunk: rows co, k in [kk, kk+32). Swizzle 16B units by (co&3).
#pragma unroll
        for (int p = 0; p < 4; ++p) {
            const int co  = p * 64 + (tid >> 2);
            const int kb8 = (tid & 3) * 8;  // ushort offset within row
            u32x4 vv = *(const u32x4*)(g_w1eff + co * CH + kk + kb8);
            *(u32x4*)(&sW[co * 32 + (kb8 ^ ((co & 3) << 3))]) = vv;
        }
        __syncthreads();

        bf16x8 af[4], bfr[4];
        const int kgrp = (lane >> 4) * 8;  // k sub-offset per 16-lane group
#pragma unroll
        for (int mi = 0; mi < 4; ++mi) {
            const int co = m0 + mi * 16 + (lane & 15);
            af[mi] = *(const bf16x8*)(&sW[co * 32 + (kgrp ^ ((co & 3) << 3))]);
        }
        const int cin = kk + kgrp;
#pragma unroll
        for (int ni = 0; ni < 4; ++ni) {
            const int tr = ni * 16 + (lane & 15) + 2;  // sA row for t = ni*16+(lane&15)
            bfr[ni] = *(const bf16x8*)(&sA[tr * CH + (cin ^ ((tr & 7) << 3))]);
        }
#pragma unroll
        for (int mi = 0; mi < 4; ++mi)
#pragma unroll
            for (int ni = 0; ni < 4; ++ni)
                acc[mi][ni] = __builtin_amdgcn_mfma_f32_16x16x32_bf16(af[mi], bfr[ni], acc[mi][ni], 0, 0, 0);
    }

    // Epilogue: D layout (m89): col = lane&15, row = (lane>>4)*4 + reg.
    const int colt = lane & 15;
    const int rg   = (lane >> 4) * 4;
    float* __restrict__ ob = out + (size_t)b * CH * TLEN;

#pragma unroll
    for (int mi = 0; mi < 4; ++mi) {
#pragma unroll
        for (int r = 0; r < 4; ++r) {
            const int c = m0 + mi * 16 + rg + r;
            const float tp0 = sTap[0 * CH + c];
            const float tp1 = sTap[1 * CH + c];
            const float tp2 = sTap[2 * CH + c];
            const float tp3 = sTap[3 * CH + c];
            const float tp4 = sTap[4 * CH + c];
            const float bias = sBias[c];
            const float* xr   = xb + (size_t)c * TLEN;
            float*       orow = ob + (size_t)c * TLEN;
#pragma unroll
            for (int ni = 0; ni < 4; ++ni) {
                const int t  = ni * 16 + colt;
                const int gt = t0 + t;
                float s = acc[mi][ni][r];
                // a[c, gt-2 .. gt+2] are sA rows t .. t+4
                const float a0 = bf16_to_f32(sA[(t + 0) * CH + (c ^ (((t + 0) & 7) << 3))]);
                const float a1 = bf16_to_f32(sA[(t + 1) * CH + (c ^ (((t + 1) & 7) << 3))]);
                const float a2 = bf16_to_f32(sA[(t + 2) * CH + (c ^ (((t + 2) & 7) << 3))]);
                const float a3 = bf16_to_f32(sA[(t + 3) * CH + (c ^ (((t + 3) & 7) << 3))]);
                const float a4 = bf16_to_f32(sA[(t + 4) * CH + (c ^ (((t + 4) & 7) << 3))]);
                float d = tp0 * a0;
                d = fmaf(tp1, a1, d);
                d = fmaf(tp2, a2, d);
                d = fmaf(tp3, a3, d);
                d = fmaf(tp4, a4, d);
                orow[gt] = s + d + bias + xr[gt];
            }
        }
    }
}

extern "C" void kernel_launch(void* const* d_in, const int* in_sizes, int n_in,
                              void* d_out, int out_size, void* d_ws, size_t ws_size,
                              hipStream_t stream) {
    const float* x  = (const float*)d_in[0];
    const float* w1 = (const float*)d_in[1];
    const float* b1 = (const float*)d_in[2];
    const float* w3 = (const float*)d_in[3];
    const float* b3 = (const float*)d_in[4];
    const float* w5 = (const float*)d_in[5];
    const float* b5 = (const float*)d_in[6];
    const float* wc = (const float*)d_in[7];
    const float* bc = (const float*)d_in[8];
    float* out = (float*)d_out;

    prep_kernel<<<dim3(CH), dim3(CH), 0, stream>>>(w1, b1, w3, b3, w5, b5, wc, bc);
    fused_kernel<<<dim3(TLEN / TN, BATCH), dim3(256), 0, stream>>>(x, out);
}

// Round 5
// 210.437 us; speedup vs baseline: 1.2951x; 1.2951x over previous
//
#include <hip/hip_runtime.h>
#include <stdint.h>

#define BATCH 32
#define CH    256
#define TLEN  4096
#define TN    64

typedef short    bf16x8 __attribute__((ext_vector_type(8)));
typedef float    f32x4  __attribute__((ext_vector_type(4)));
typedef uint16_t u16x4  __attribute__((ext_vector_type(4)));

__device__ __attribute__((aligned(16))) uint16_t g_w1eff[CH * CH];
__device__ __attribute__((aligned(16))) float g_tap[5 * CH];   // tap-major: g_tap[j*CH + c]
__device__ __attribute__((aligned(16))) float g_bias[CH];

static __device__ __forceinline__ uint16_t f32_to_bf16(float f) {
    uint32_t u = __builtin_bit_cast(uint32_t, f);
    u += 0x7FFFu + ((u >> 16) & 1u);
    return (uint16_t)(u >> 16);
}
static __device__ __forceinline__ float bf16_to_f32(uint16_t h) {
    uint32_t u = ((uint32_t)h) << 16;
    return __builtin_bit_cast(float, u);
}
static __device__ __forceinline__ float gelu_exact(float v) {
    return 0.5f * v * (1.0f + erff(v * 0.70710678118654752f));
}

// Precompute: w1eff[o][c] = wc0[o]*w1[o][c] (bf16); 5-tap g (tap-major); fused bias.
__global__ void prep_kernel(const float* __restrict__ w1, const float* __restrict__ b1,
                            const float* __restrict__ w3, const float* __restrict__ b3,
                            const float* __restrict__ w5, const float* __restrict__ b5,
                            const float* __restrict__ wc, const float* __restrict__ bc) {
    const int o = blockIdx.x;
    const int c = threadIdx.x;
    const float wc0 = wc[o * 3 + 0];
    g_w1eff[o * CH + c] = f32_to_bf16(wc0 * w1[o * CH + c]);
    if (c == 0) {
        const float wc1 = wc[o * 3 + 1], wc2 = wc[o * 3 + 2];
        g_tap[0 * CH + o] = wc2 * w5[o * 5 + 0];
        g_tap[1 * CH + o] = wc1 * w3[o * 3 + 0] + wc2 * w5[o * 5 + 1];
        g_tap[2 * CH + o] = wc1 * w3[o * 3 + 1] + wc2 * w5[o * 5 + 2];
        g_tap[3 * CH + o] = wc1 * w3[o * 3 + 2] + wc2 * w5[o * 5 + 3];
        g_tap[4 * CH + o] = wc2 * w5[o * 5 + 4];
        g_bias[o] = wc0 * b1[o] + wc1 * b3[o] + wc2 * b5[o] + bc[o];
    }
}

// Per block = one (batch b, 64-timestep tile). LDS holds ONLY the gelu(x) tile
// [t=0..67][c=0..255] bf16, t-major, XOR-swizzled: (t,c) -> sA[t*256 + (c^((t&7)<<3))].
// Weights are read straight from global (L2-resident, 128 KB total).
// Exactly ONE __syncthreads per block.
__global__ __launch_bounds__(256, 4)
void fused_kernel(const float* __restrict__ x, float* __restrict__ out) {
    __shared__ __attribute__((aligned(16))) uint16_t sA[68 * CH];   // 34816 B

    const int tid  = threadIdx.x;
    const int lane = tid & 63;
    const int wid  = tid >> 6;
    const int b    = blockIdx.y;
    const int t0   = blockIdx.x * TN;

    const float* __restrict__ xb = x + (size_t)b * CH * TLEN;

    // Stage a = gelu(x) tile with +/-2 halo. Wave w handles channels w, w+4, ...
    for (int c = wid; c < CH; c += 4) {
        const float* xr = xb + (size_t)c * TLEN;
        {
            const int ti = lane;
            const int gt = t0 - 2 + ti;
            float v = (gt >= 0 && gt < TLEN) ? xr[gt] : 0.0f;
            sA[ti * CH + (c ^ ((ti & 7) << 3))] = f32_to_bf16(gelu_exact(v));
        }
        if (lane < 4) {
            const int ti = 64 + lane;
            const int gt = t0 - 2 + ti;
            float v = (gt < TLEN) ? xr[gt] : 0.0f;
            sA[ti * CH + (c ^ ((ti & 7) << 3))] = f32_to_bf16(gelu_exact(v));
        }
    }
    __syncthreads();

    f32x4 acc[4][4];
    const f32x4 vzero = {0.f, 0.f, 0.f, 0.f};
#pragma unroll
    for (int mi = 0; mi < 4; ++mi)
#pragma unroll
        for (int ni = 0; ni < 4; ++ni) acc[mi][ni] = vzero;

    const int m0   = wid * 64;
    const int kgrp = (lane >> 4) * 8;  // k sub-offset per 16-lane group

    // Barrier-free K loop: weight fragments from global (L2), activations from LDS.
#pragma unroll
    for (int kk = 0; kk < CH; kk += 32) {
        bf16x8 af[4], bfr[4];
#pragma unroll
        for (int mi = 0; mi < 4; ++mi) {
            const int co = m0 + mi * 16 + (lane & 15);
            af[mi] = *(const bf16x8*)(g_w1eff + co * CH + kk + kgrp);
        }
        const int cin = kk + kgrp;
#pragma unroll
        for (int ni = 0; ni < 4; ++ni) {
            const int tr = ni * 16 + (lane & 15) + 2;  // sA row for t = ni*16+(lane&15)
            bfr[ni] = *(const bf16x8*)(&sA[tr * CH + (cin ^ ((tr & 7) << 3))]);
        }
#pragma unroll
        for (int mi = 0; mi < 4; ++mi)
#pragma unroll
            for (int ni = 0; ni < 4; ++ni)
                acc[mi][ni] = __builtin_amdgcn_mfma_f32_16x16x32_bf16(af[mi], bfr[ni], acc[mi][ni], 0, 0, 0);
    }

    // Epilogue: D layout: col(t) = lane&15, row(c) = (lane>>4)*4 + reg.
    const int colt = lane & 15;
    const int rg   = (lane >> 4) * 4;
    float* __restrict__ ob = out + (size_t)b * CH * TLEN;

#pragma unroll
    for (int mi = 0; mi < 4; ++mi) {
        const int c = m0 + mi * 16 + rg;           // 4 channels c..c+3, 4-aligned
        const f32x4 tp0 = *(const f32x4*)(g_tap + 0 * CH + c);
        const f32x4 tp1 = *(const f32x4*)(g_tap + 1 * CH + c);
        const f32x4 tp2 = *(const f32x4*)(g_tap + 2 * CH + c);
        const f32x4 tp3 = *(const f32x4*)(g_tap + 3 * CH + c);
        const f32x4 tp4 = *(const f32x4*)(g_tap + 4 * CH + c);
        const f32x4 bsv = *(const f32x4*)(g_bias + c);
#pragma unroll
        for (int ni = 0; ni < 4; ++ni) {
            const int t  = ni * 16 + colt;         // tile-local time
            const int gt = t0 + t;
            // a[c..c+3][gt-2 .. gt+2] are sA rows t .. t+4 (halo offset +2 built in)
            u16x4 a0 = *(const u16x4*)(&sA[(t + 0) * CH + (c ^ (((t + 0) & 7) << 3))]);
            u16x4 a1 = *(const u16x4*)(&sA[(t + 1) * CH + (c ^ (((t + 1) & 7) << 3))]);
            u16x4 a2 = *(const u16x4*)(&sA[(t + 2) * CH + (c ^ (((t + 2) & 7) << 3))]);
            u16x4 a3 = *(const u16x4*)(&sA[(t + 3) * CH + (c ^ (((t + 3) & 7) << 3))]);
            u16x4 a4 = *(const u16x4*)(&sA[(t + 4) * CH + (c ^ (((t + 4) & 7) << 3))]);
#pragma unroll
            for (int r = 0; r < 4; ++r) {
                float d = tp0[r] * bf16_to_f32(a0[r]);
                d = fmaf(tp1[r], bf16_to_f32(a1[r]), d);
                d = fmaf(tp2[r], bf16_to_f32(a2[r]), d);
                d = fmaf(tp3[r], bf16_to_f32(a3[r]), d);
                d = fmaf(tp4[r], bf16_to_f32(a4[r]), d);
                const size_t off = (size_t)(c + r) * TLEN + gt;
                ob[off] = acc[mi][ni][r] + d + bsv[r] + xb[off];
            }
        }
    }
}

extern "C" void kernel_launch(void* const* d_in, const int* in_sizes, int n_in,
                              void* d_out, int out_size, void* d_ws, size_t ws_size,
                              hipStream_t stream) {
    const float* x  = (const float*)d_in[0];
    const float* w1 = (const float*)d_in[1];
    const float* b1 = (const float*)d_in[2];
    const float* w3 = (const float*)d_in[3];
    const float* b3 = (const float*)d_in[4];
    const float* w5 = (const float*)d_in[5];
    const float* b5 = (const float*)d_in[6];
    const float* wc = (const float*)d_in[7];
    const float* bc = (const float*)d_in[8];
    float* out = (float*)d_out;

    prep_kernel<<<dim3(CH), dim3(CH), 0, stream>>>(w1, b1, w3, b3, w5, b5, wc, bc);
    fused_kernel<<<dim3(TLEN / TN, BATCH), dim3(256), 0, stream>>>(x, out);
}

// Round 6
// 148.971 us; speedup vs baseline: 1.8295x; 1.4126x over previous
//
#include <hip/hip_runtime.h>
#include <stdint.h>

#define BATCH 32
#define CH    256
#define TLEN  4096
#define TN    64

typedef short    bf16x8 __attribute__((ext_vector_type(8)));
typedef float    f32x4  __attribute__((ext_vector_type(4)));
typedef uint16_t u16x4  __attribute__((ext_vector_type(4)));

__device__ __attribute__((aligned(16))) uint16_t g_w1eff[CH * CH];
__device__ __attribute__((aligned(16))) float g_tap[5 * CH];   // tap-major: g_tap[j*CH + c]
__device__ __attribute__((aligned(16))) float g_bias[CH];

static __device__ __forceinline__ uint16_t f32_to_bf16(float f) {
    uint32_t u = __builtin_bit_cast(uint32_t, f);
    u += 0x7FFFu + ((u >> 16) & 1u);
    return (uint16_t)(u >> 16);
}
static __device__ __forceinline__ float bf16_to_f32(uint16_t h) {
    uint32_t u = ((uint32_t)h) << 16;
    return __builtin_bit_cast(float, u);
}
// exact-erf gelu for the tiny prep path
static __device__ __forceinline__ float gelu_exact(float v) {
    return 0.5f * v * (1.0f + erff(v * 0.70710678118654752f));
}
// tanh-form gelu, folded into exp2: gelu ~= x - x / (1 + 2^(x*(A + B*x^2)))
// A = 2*0.7978845608*log2(e), B = A*0.044715. Max abs err vs exact-erf ~3e-3.
static __device__ __forceinline__ float gelu_fast(float x) {
    const float A = 2.3022082f;
    const float B = 0.10294331f;
    float x2 = x * x;
    float z  = x * fmaf(x2, B, A);
    float e  = exp2f(z);                       // v_exp_f32
    float r  = __builtin_amdgcn_rcpf(1.0f + e); // v_rcp_f32
    return fmaf(-x, r, x);
}

// Precompute: w1eff[o][c] = wc0[o]*w1[o][c] (bf16); 5-tap g (tap-major); fused bias.
__global__ void prep_kernel(const float* __restrict__ w1, const float* __restrict__ b1,
                            const float* __restrict__ w3, const float* __restrict__ b3,
                            const float* __restrict__ w5, const float* __restrict__ b5,
                            const float* __restrict__ wc, const float* __restrict__ bc) {
    const int o = blockIdx.x;
    const int c = threadIdx.x;
    const float wc0 = wc[o * 3 + 0];
    g_w1eff[o * CH + c] = f32_to_bf16(wc0 * w1[o * CH + c]);
    if (c == 0) {
        const float wc1 = wc[o * 3 + 1], wc2 = wc[o * 3 + 2];
        g_tap[0 * CH + o] = wc2 * w5[o * 5 + 0];
        g_tap[1 * CH + o] = wc1 * w3[o * 3 + 0] + wc2 * w5[o * 5 + 1];
        g_tap[2 * CH + o] = wc1 * w3[o * 3 + 1] + wc2 * w5[o * 5 + 2];
        g_tap[3 * CH + o] = wc1 * w3[o * 3 + 2] + wc2 * w5[o * 5 + 3];
        g_tap[4 * CH + o] = wc2 * w5[o * 5 + 4];
        g_bias[o] = wc0 * b1[o] + wc1 * b3[o] + wc2 * b5[o] + bc[o];
    }
}

// Per block = one (batch b, 64-timestep tile). LDS holds ONLY the gelu(x) tile
// [t=0..67][c=0..255] bf16, t-major, XOR-swizzled: (t,c) -> sA[t*256 + (c^((t&7)<<3))].
// Staging: per wave, 8 groups of 8 consecutive channels; 8 coalesced 256-B global
// loads (lane->t), 8 fast-gelus, ONE ds_write_b128 (group stays contiguous under
// the swizzle since cb%8==0). Halo (t=64..67) in a separate full-lane pass.
__global__ __launch_bounds__(256, 4)
void fused_kernel(const float* __restrict__ x, float* __restrict__ out) {
    __shared__ __attribute__((aligned(16))) uint16_t sA[68 * CH];   // 34816 B

    const int tid  = threadIdx.x;
    const int lane = tid & 63;
    const int wid  = tid >> 6;
    const int b    = blockIdx.y;
    const int t0   = blockIdx.x * TN;

    const float* __restrict__ xb = x + (size_t)b * CH * TLEN;

    // ---- main staging pass: rows ti = 0..63 (gt = t0-2+lane) ----
    {
        const int gt = t0 - 2 + lane;
        const int c0 = wid * 64;
        if (blockIdx.x > 0) {   // interior: no bounds check needed (gt in [62, 4093])
#pragma unroll
            for (int g = 0; g < 8; ++g) {
                const int cb = c0 + g * 8;
                const float* xp = xb + (size_t)cb * TLEN + gt;
                bf16x8 pk;
#pragma unroll
                for (int j = 0; j < 8; ++j)
                    pk[j] = (short)f32_to_bf16(gelu_fast(xp[(size_t)j * TLEN]));
                *(bf16x8*)(&sA[lane * CH + (cb ^ ((lane & 7) << 3))]) = pk;
            }
        } else {                // first tile: gt may be -2,-1
#pragma unroll
            for (int g = 0; g < 8; ++g) {
                const int cb = c0 + g * 8;
                const float* xp = xb + (size_t)cb * TLEN + gt;
                bf16x8 pk;
#pragma unroll
                for (int j = 0; j < 8; ++j) {
                    float v = (gt >= 0) ? xp[(size_t)j * TLEN] : 0.0f;
                    pk[j] = (short)f32_to_bf16(gelu_fast(v));
                }
                *(bf16x8*)(&sA[lane * CH + (cb ^ ((lane & 7) << 3))]) = pk;
            }
        }
    }
    // ---- halo pass: rows ti = 64..67 (gt = t0+62..t0+65), c = tid ----
    {
        const int c = tid;
        if (blockIdx.x < gridDim.x - 1) {
#pragma unroll
            for (int k = 0; k < 4; ++k) {
                float v = xb[(size_t)c * TLEN + (t0 + 62 + k)];
                sA[(64 + k) * CH + (c ^ (k << 3))] = f32_to_bf16(gelu_fast(v));
            }
        } else {
#pragma unroll
            for (int k = 0; k < 4; ++k) {
                const int gt = t0 + 62 + k;
                float v = (gt < TLEN) ? xb[(size_t)c * TLEN + gt] : 0.0f;
                sA[(64 + k) * CH + (c ^ (k << 3))] = f32_to_bf16(gelu_fast(v));
            }
        }
    }
    __syncthreads();

    f32x4 acc[4][4];
    const f32x4 vzero = {0.f, 0.f, 0.f, 0.f};
#pragma unroll
    for (int mi = 0; mi < 4; ++mi)
#pragma unroll
        for (int ni = 0; ni < 4; ++ni) acc[mi][ni] = vzero;

    const int m0   = wid * 64;
    const int kgrp = (lane >> 4) * 8;  // k sub-offset per 16-lane group

    // Barrier-free K loop: weight fragments from global (L2), activations from LDS.
#pragma unroll
    for (int kk = 0; kk < CH; kk += 32) {
        bf16x8 af[4], bfr[4];
#pragma unroll
        for (int mi = 0; mi < 4; ++mi) {
            const int co = m0 + mi * 16 + (lane & 15);
            af[mi] = *(const bf16x8*)(g_w1eff + co * CH + kk + kgrp);
        }
        const int cin = kk + kgrp;
#pragma unroll
        for (int ni = 0; ni < 4; ++ni) {
            const int tr = ni * 16 + (lane & 15) + 2;  // sA row for t = ni*16+(lane&15)
            bfr[ni] = *(const bf16x8*)(&sA[tr * CH + (cin ^ ((tr & 7) << 3))]);
        }
#pragma unroll
        for (int mi = 0; mi < 4; ++mi)
#pragma unroll
            for (int ni = 0; ni < 4; ++ni)
                acc[mi][ni] = __builtin_amdgcn_mfma_f32_16x16x32_bf16(af[mi], bfr[ni], acc[mi][ni], 0, 0, 0);
    }

    // Epilogue: D layout: col(t) = lane&15, row(c) = (lane>>4)*4 + reg.
    const int colt = lane & 15;
    const int rg   = (lane >> 4) * 4;
    float* __restrict__ ob = out + (size_t)b * CH * TLEN;

#pragma unroll
    for (int mi = 0; mi < 4; ++mi) {
        const int c = m0 + mi * 16 + rg;           // 4 channels c..c+3, 4-aligned
        const f32x4 tp0 = *(const f32x4*)(g_tap + 0 * CH + c);
        const f32x4 tp1 = *(const f32x4*)(g_tap + 1 * CH + c);
        const f32x4 tp2 = *(const f32x4*)(g_tap + 2 * CH + c);
        const f32x4 tp3 = *(const f32x4*)(g_tap + 3 * CH + c);
        const f32x4 tp4 = *(const f32x4*)(g_tap + 4 * CH + c);
        const f32x4 bsv = *(const f32x4*)(g_bias + c);
#pragma unroll
        for (int ni = 0; ni < 4; ++ni) {
            const int t  = ni * 16 + colt;         // tile-local time
            const int gt = t0 + t;
            // a[c..c+3][gt-2 .. gt+2] are sA rows t .. t+4 (halo offset +2 built in)
            u16x4 a0 = *(const u16x4*)(&sA[(t + 0) * CH + (c ^ (((t + 0) & 7) << 3))]);
            u16x4 a1 = *(const u16x4*)(&sA[(t + 1) * CH + (c ^ (((t + 1) & 7) << 3))]);
            u16x4 a2 = *(const u16x4*)(&sA[(t + 2) * CH + (c ^ (((t + 2) & 7) << 3))]);
            u16x4 a3 = *(const u16x4*)(&sA[(t + 3) * CH + (c ^ (((t + 3) & 7) << 3))]);
            u16x4 a4 = *(const u16x4*)(&sA[(t + 4) * CH + (c ^ (((t + 4) & 7) << 3))]);
#pragma unroll
            for (int r = 0; r < 4; ++r) {
                float d = tp0[r] * bf16_to_f32(a0[r]);
                d = fmaf(tp1[r], bf16_to_f32(a1[r]), d);
                d = fmaf(tp2[r], bf16_to_f32(a2[r]), d);
                d = fmaf(tp3[r], bf16_to_f32(a3[r]), d);
                d = fmaf(tp4[r], bf16_to_f32(a4[r]), d);
                const size_t off = (size_t)(c + r) * TLEN + gt;
                ob[off] = acc[mi][ni][r] + d + bsv[r] + xb[off];
            }
        }
    }
}

extern "C" void kernel_launch(void* const* d_in, const int* in_sizes, int n_in,
                              void* d_out, int out_size, void* d_ws, size_t ws_size,
                              hipStream_t stream) {
    const float* x  = (const float*)d_in[0];
    const float* w1 = (const float*)d_in[1];
    const float* b1 = (const float*)d_in[2];
    const float* w3 = (const float*)d_in[3];
    const float* b3 = (const float*)d_in[4];
    const float* w5 = (const float*)d_in[5];
    const float* b5 = (const float*)d_in[6];
    const float* wc = (const float*)d_in[7];
    const float* bc = (const float*)d_in[8];
    float* out = (float*)d_out;

    prep_kernel<<<dim3(CH), dim3(CH), 0, stream>>>(w1, b1, w3, b3, w5, b5, wc, bc);
    fused_kernel<<<dim3(TLEN / TN, BATCH), dim3(256), 0, stream>>>(x, out);
}

// Round 7
// 131.021 us; speedup vs baseline: 2.0802x; 1.1370x over previous
//
#include <hip/hip_runtime.h>
#include <stdint.h>

#define BATCH 32
#define CH    256
#define TLEN  4096
#define TN    64

typedef short    bf16x8 __attribute__((ext_vector_type(8)));
typedef float    f32x4  __attribute__((ext_vector_type(4)));
typedef uint16_t u16x4  __attribute__((ext_vector_type(4)));

__device__ __attribute__((aligned(16))) uint16_t g_w1eff[CH * CH];
__device__ __attribute__((aligned(16))) float g_tap[5 * CH];   // tap-major: g_tap[j*CH + c]
__device__ __attribute__((aligned(16))) float g_bias[CH];

static __device__ __forceinline__ uint16_t f32_to_bf16(float f) {
    uint32_t u = __builtin_bit_cast(uint32_t, f);
    u += 0x7FFFu + ((u >> 16) & 1u);
    return (uint16_t)(u >> 16);
}
static __device__ __forceinline__ float bf16_to_f32(uint16_t h) {
    uint32_t u = ((uint32_t)h) << 16;
    return __builtin_bit_cast(float, u);
}
// tanh-form gelu folded into exp2: gelu ~= x - x / (1 + 2^(x*(A + B*x^2)))
// A = 2*0.7978845608*log2(e), B = A*0.044715. Max abs err vs exact-erf ~3e-3.
static __device__ __forceinline__ float gelu_fast(float x) {
    const float A = 2.3022082f;
    const float B = 0.10294331f;
    float x2 = x * x;
    float z  = x * fmaf(x2, B, A);
    float e  = exp2f(z);                        // v_exp_f32
    float r  = __builtin_amdgcn_rcpf(1.0f + e); // v_rcp_f32
    return fmaf(-x, r, x);
}

// Precompute: w1eff[o][c] = wc0[o]*w1[o][c] (bf16); 5-tap g (tap-major); fused bias.
__global__ void prep_kernel(const float* __restrict__ w1, const float* __restrict__ b1,
                            const float* __restrict__ w3, const float* __restrict__ b3,
                            const float* __restrict__ w5, const float* __restrict__ b5,
                            const float* __restrict__ wc, const float* __restrict__ bc) {
    const int o = blockIdx.x;
    const int c = threadIdx.x;
    const float wc0 = wc[o * 3 + 0];
    g_w1eff[o * CH + c] = f32_to_bf16(wc0 * w1[o * CH + c]);
    if (c == 0) {
        const float wc1 = wc[o * 3 + 1], wc2 = wc[o * 3 + 2];
        g_tap[0 * CH + o] = wc2 * w5[o * 5 + 0];
        g_tap[1 * CH + o] = wc1 * w3[o * 3 + 0] + wc2 * w5[o * 5 + 1];
        g_tap[2 * CH + o] = wc1 * w3[o * 3 + 1] + wc2 * w5[o * 5 + 2];
        g_tap[3 * CH + o] = wc1 * w3[o * 3 + 2] + wc2 * w5[o * 5 + 3];
        g_tap[4 * CH + o] = wc2 * w5[o * 5 + 4];
        g_bias[o] = wc0 * b1[o] + wc1 * b3[o] + wc2 * b5[o] + bc[o];
    }
}

// Per block = one (batch b, 64-timestep tile).
// sA: gelu(x) tile [t=0..67][c=0..255] bf16, t-major, XOR-swizzled.
// sT: per-wave 16x64 f32 transpose scratch, row stride 68 (2-way write banks = free,
//     rows 16B-aligned: 68*4B = 272B % 16 == 0).
__global__ __launch_bounds__(256, 3)
void fused_kernel(const float* __restrict__ x, float* __restrict__ out) {
    __shared__ __attribute__((aligned(16))) uint16_t sA[68 * CH];     // 34816 B
    __shared__ __attribute__((aligned(16))) float    sT[4 * 16 * 68]; // 17408 B

    const int tid  = threadIdx.x;
    const int lane = tid & 63;
    const int wid  = tid >> 6;
    const int b    = blockIdx.y;
    const int t0   = blockIdx.x * TN;

    const float* __restrict__ xb = x + (size_t)b * CH * TLEN;

    // ---- main staging pass: rows ti = 0..63 (gt = t0-2+lane) ----
    {
        const int gt = t0 - 2 + lane;
        const int c0 = wid * 64;
        if (blockIdx.x > 0) {   // interior: gt in [62, 4093]
#pragma unroll
            for (int g = 0; g < 8; ++g) {
                const int cb = c0 + g * 8;
                const float* xp = xb + (size_t)cb * TLEN + gt;
                bf16x8 pk;
#pragma unroll
                for (int j = 0; j < 8; ++j)
                    pk[j] = (short)f32_to_bf16(gelu_fast(xp[(size_t)j * TLEN]));
                *(bf16x8*)(&sA[lane * CH + (cb ^ ((lane & 7) << 3))]) = pk;
            }
        } else {                // first tile: gt may be -2,-1
#pragma unroll
            for (int g = 0; g < 8; ++g) {
                const int cb = c0 + g * 8;
                const float* xp = xb + (size_t)cb * TLEN + gt;
                bf16x8 pk;
#pragma unroll
                for (int j = 0; j < 8; ++j) {
                    float v = (gt >= 0) ? xp[(size_t)j * TLEN] : 0.0f;
                    pk[j] = (short)f32_to_bf16(gelu_fast(v));
                }
                *(bf16x8*)(&sA[lane * CH + (cb ^ ((lane & 7) << 3))]) = pk;
            }
        }
    }
    // ---- halo pass: rows ti = 64..67 (gt = t0+62..t0+65), c = tid ----
    {
        const int c = tid;
        if (blockIdx.x < gridDim.x - 1) {
#pragma unroll
            for (int k = 0; k < 4; ++k) {
                float v = xb[(size_t)c * TLEN + (t0 + 62 + k)];
                sA[(64 + k) * CH + (c ^ (k << 3))] = f32_to_bf16(gelu_fast(v));
            }
        } else {
#pragma unroll
            for (int k = 0; k < 4; ++k) {
                const int gt = t0 + 62 + k;
                float v = (gt < TLEN) ? xb[(size_t)c * TLEN + gt] : 0.0f;
                sA[(64 + k) * CH + (c ^ (k << 3))] = f32_to_bf16(gelu_fast(v));
            }
        }
    }
    __syncthreads();

    f32x4 acc[4][4];
    const f32x4 vzero = {0.f, 0.f, 0.f, 0.f};
#pragma unroll
    for (int mi = 0; mi < 4; ++mi)
#pragma unroll
        for (int ni = 0; ni < 4; ++ni) acc[mi][ni] = vzero;

    const int m0   = wid * 64;
    const int kgrp = (lane >> 4) * 8;  // k sub-offset per 16-lane group

    // Barrier-free K loop: weight fragments from global (L2), activations from LDS.
#pragma unroll
    for (int kk = 0; kk < CH; kk += 32) {
        bf16x8 af[4], bfr[4];
#pragma unroll
        for (int mi = 0; mi < 4; ++mi) {
            const int co = m0 + mi * 16 + (lane & 15);
            af[mi] = *(const bf16x8*)(g_w1eff + co * CH + kk + kgrp);
        }
        const int cin = kk + kgrp;
#pragma unroll
        for (int ni = 0; ni < 4; ++ni) {
            const int tr = ni * 16 + (lane & 15) + 2;  // sA row for t = ni*16+(lane&15)
            bfr[ni] = *(const bf16x8*)(&sA[tr * CH + (cin ^ ((tr & 7) << 3))]);
        }
#pragma unroll
        for (int mi = 0; mi < 4; ++mi)
#pragma unroll
            for (int ni = 0; ni < 4; ++ni)
                acc[mi][ni] = __builtin_amdgcn_mfma_f32_16x16x32_bf16(af[mi], bfr[ni], acc[mi][ni], 0, 0, 0);
    }

    // Epilogue. MFMA D layout: col(t) = lane&15, row(c) = (lane>>4)*4 + reg.
    // Phase A (per mi): s + depthwise + bias -> sT[wave][c_local][t]
    // Phase B (per mi): lane = c_idx*4 + q streams 16 t as 4x f32x4: sT + x -> out
    const int colt = lane & 15;
    const int rg   = (lane >> 4) * 4;
    float* __restrict__ ob  = out + (size_t)b * CH * TLEN;
    float* __restrict__ sTw = sT + wid * (16 * 68);

    const int ci = lane >> 2;          // 0..15 channel-local for phase B
    const int q  = lane & 3;           // 0..3 t-quad

#pragma unroll
    for (int mi = 0; mi < 4; ++mi) {
        const int c = m0 + mi * 16 + rg;           // 4 channels c..c+3, 4-aligned
        const f32x4 tp0 = *(const f32x4*)(g_tap + 0 * CH + c);
        const f32x4 tp1 = *(const f32x4*)(g_tap + 1 * CH + c);
        const f32x4 tp2 = *(const f32x4*)(g_tap + 2 * CH + c);
        const f32x4 tp3 = *(const f32x4*)(g_tap + 3 * CH + c);
        const f32x4 tp4 = *(const f32x4*)(g_tap + 4 * CH + c);
        const f32x4 bsv = *(const f32x4*)(g_bias + c);
#pragma unroll
        for (int ni = 0; ni < 4; ++ni) {
            const int t = ni * 16 + colt;          // tile-local time
            u16x4 a0 = *(const u16x4*)(&sA[(t + 0) * CH + (c ^ (((t + 0) & 7) << 3))]);
            u16x4 a1 = *(const u16x4*)(&sA[(t + 1) * CH + (c ^ (((t + 1) & 7) << 3))]);
            u16x4 a2 = *(const u16x4*)(&sA[(t + 2) * CH + (c ^ (((t + 2) & 7) << 3))]);
            u16x4 a3 = *(const u16x4*)(&sA[(t + 3) * CH + (c ^ (((t + 3) & 7) << 3))]);
            u16x4 a4 = *(const u16x4*)(&sA[(t + 4) * CH + (c ^ (((t + 4) & 7) << 3))]);
#pragma unroll
            for (int r = 0; r < 4; ++r) {
                float d = tp0[r] * bf16_to_f32(a0[r]);
                d = fmaf(tp1[r], bf16_to_f32(a1[r]), d);
                d = fmaf(tp2[r], bf16_to_f32(a2[r]), d);
                d = fmaf(tp3[r], bf16_to_f32(a3[r]), d);
                d = fmaf(tp4[r], bf16_to_f32(a4[r]), d);
                sTw[(rg + r) * 68 + t] = acc[mi][ni][r] + d + bsv[r];
            }
        }
        // Phase B: issue residual loads before the barrier so they overlap it.
        const int cc = m0 + mi * 16 + ci;
        const float* xrow = xb + (size_t)cc * TLEN + t0 + q * 16;
        float*       orow = ob + (size_t)cc * TLEN + t0 + q * 16;
        f32x4 xv0 = *(const f32x4*)(xrow + 0);
        f32x4 xv1 = *(const f32x4*)(xrow + 4);
        f32x4 xv2 = *(const f32x4*)(xrow + 8);
        f32x4 xv3 = *(const f32x4*)(xrow + 12);
        __syncthreads();
        const float* srow = sTw + ci * 68 + q * 16;
        f32x4 s0 = *(const f32x4*)(srow + 0);
        f32x4 s1 = *(const f32x4*)(srow + 4);
        f32x4 s2 = *(const f32x4*)(srow + 8);
        f32x4 s3 = *(const f32x4*)(srow + 12);
        *(f32x4*)(orow + 0)  = s0 + xv0;
        *(f32x4*)(orow + 4)  = s1 + xv1;
        *(f32x4*)(orow + 8)  = s2 + xv2;
        *(f32x4*)(orow + 12) = s3 + xv3;
        __syncthreads();   // scratch reused next mi
    }
}

extern "C" void kernel_launch(void* const* d_in, const int* in_sizes, int n_in,
                              void* d_out, int out_size, void* d_ws, size_t ws_size,
                              hipStream_t stream) {
    const float* x  = (const float*)d_in[0];
    const float* w1 = (const float*)d_in[1];
    const float* b1 = (const float*)d_in[2];
    const float* w3 = (const float*)d_in[3];
    const float* b3 = (const float*)d_in[4];
    const float* w5 = (const float*)d_in[5];
    const float* b5 = (const float*)d_in[6];
    const float* wc = (const float*)d_in[7];
    const float* bc = (const float*)d_in[8];
    float* out = (float*)d_out;

    prep_kernel<<<dim3(CH), dim3(CH), 0, stream>>>(w1, b1, w3, b3, w5, b5, wc, bc);
    fused_kernel<<<dim3(TLEN / TN, BATCH), dim3(256), 0, stream>>>(x, out);
}